// Round 19
// baseline (37.103 us; speedup 1.0000x reference)
//
#include <hip/hip_runtime.h>
#include <hip/hip_bf16.h>

// Problem dims (fixed): B=8, Q=256, K=256, D=256, H=256, DV=512
#define B_  8
#define Q_  256
#define K_  256
#define D_  256
#define H_  256
#define DV_ 512
#define QB  2            // q-rows per score block

#define SCALE_2LOG2E 2.8853900817779268f   // 2*log2(e): exp(2x) = 2^(x*this)
#define LOG2E_F      1.4426950408889634f

typedef __attribute__((ext_vector_type(8))) short bf16x8;   // 8 bf16 = 4 VGPR
typedef __attribute__((ext_vector_type(4))) float f32x4;    // MFMA C/D

__device__ __forceinline__ uint f2bf(float f) {             // RNE f32->bf16
  uint u = __float_as_uint(f);
  return (u + 0x7FFFu + ((u >> 16) & 1u)) >> 16;
}
__device__ __forceinline__ uint pk(float lo, float hi) {
  return f2bf(lo) | (f2bf(hi) << 16);
}

// Stage a 64x64 f32 tile (row-major, leading dim ldg, base pre-offset) into
// LDS bf16 [64][72]. Direct layout.
__device__ __forceinline__ void stage_direct(const float* g, int ldg,
                                             ushort (*lds)[72], int t) {
  const int sr = t >> 2, sc = (t & 3) * 16;
  const float* sp = g + (size_t)sr * ldg + sc;
  float4 v0 = ((const float4*)sp)[0];
  float4 v1 = ((const float4*)sp)[1];
  float4 v2 = ((const float4*)sp)[2];
  float4 v3 = ((const float4*)sp)[3];
  uint4 w0, w1;
  w0.x = pk(v0.x, v0.y); w0.y = pk(v0.z, v0.w);
  w0.z = pk(v1.x, v1.y); w0.w = pk(v1.z, v1.w);
  w1.x = pk(v2.x, v2.y); w1.y = pk(v2.z, v2.w);
  w1.z = pk(v3.x, v3.y); w1.w = pk(v3.z, v3.w);
  *(uint4*)&lds[sr][sc]     = w0;
  *(uint4*)&lds[sr][sc + 8] = w1;
}
// Stage TRANSPOSED: global [kdim][rdim] (rdim contiguous, leading dim ldg,
// base pre-offset to (k0,r0)) -> LDS [r][k] bf16 via 4x4 register transpose.
__device__ __forceinline__ void stage_trans(const float* g, int ldg,
                                            ushort (*lds)[72], int t) {
  const int kq = (t & 15) * 4, rq = (t >> 4) * 4;
  float4 a0 = *(const float4*)(g + (size_t)(kq + 0) * ldg + rq);
  float4 a1 = *(const float4*)(g + (size_t)(kq + 1) * ldg + rq);
  float4 a2 = *(const float4*)(g + (size_t)(kq + 2) * ldg + rq);
  float4 a3 = *(const float4*)(g + (size_t)(kq + 3) * ldg + rq);
  uint2 w;
  w.x = pk(a0.x, a1.x); w.y = pk(a2.x, a3.x); *(uint2*)&lds[rq + 0][kq] = w;
  w.x = pk(a0.y, a1.y); w.y = pk(a2.y, a3.y); *(uint2*)&lds[rq + 1][kq] = w;
  w.x = pk(a0.z, a1.z); w.y = pk(a2.z, a3.z); *(uint2*)&lds[rq + 2][kq] = w;
  w.x = pk(a0.w, a1.w); w.y = pk(a2.w, a3.w); *(uint2*)&lds[rq + 3][kq] = w;
}

// ---------------------------------------------------------------------------
// Kernel 1: projections + exp via bf16 MFMA (16x16x32).
//   qpath: Eq[q][h]  (f32)  = exp2( (queries @ Wq) * 2log2e )
//   kpath: EkT[h][k] (BF16) = exp2( (Wk^T @ keys^T) * 2log2e )
// EkT stored bf16: halves score's dominant traffic (r16 vs r17 showed score
// is BW/port-bound: 2x traffic with 2x occupancy gave identical time).
// C/D mapping m89-verified; A/B use the same k-window convention both sides.
// ---------------------------------------------------------------------------
__global__ __launch_bounds__(256) void proj_kernel(
    const float* __restrict__ queries, const float* __restrict__ keys,
    const float* __restrict__ Wq, const float* __restrict__ Wk,
    float* __restrict__ Eq, ushort* __restrict__ EkT) {
  const int id = blockIdx.x;
  const int b  = id & 7;                   // XCD-locality decode
  const bool kpath = (id >> 3) & 1;
  const int m0 = ((id >> 4) & 3) * 64;     // qpath: q rows; kpath: h rows
  const int n0 = ((id >> 6) & 3) * 64;     // qpath: h cols; kpath: k cols
  const int t  = threadIdx.x;

  __shared__ ushort Abuf[64][72];          // 9 KB
  __shared__ ushort Bbuf[64][72];          // 9 KB

  const int wv = t >> 6, l = t & 63, fr = l & 15, fg = l >> 4;

  f32x4 acc0 = {0.f, 0.f, 0.f, 0.f};
  f32x4 acc1 = acc0, acc2 = acc0, acc3 = acc0;

  for (int kk = 0; kk < D_; kk += 64) {
    if (!kpath) {
      stage_direct(queries + (size_t)(b * Q_ + m0) * D_ + kk, D_, Abuf, t);
      stage_trans (Wq + (size_t)kk * H_ + n0, H_, Bbuf, t);
    } else {
      stage_trans (Wk + (size_t)kk * H_ + m0, H_, Abuf, t);
      stage_direct(keys + (size_t)(b * K_ + n0) * D_ + kk, D_, Bbuf, t);
    }
    __syncthreads();
    #pragma unroll
    for (int ks = 0; ks < 2; ks++) {
      bf16x8 af = *(const bf16x8*)&Abuf[wv * 16 + fr][ks * 32 + fg * 8];
      bf16x8 b0 = *(const bf16x8*)&Bbuf[ 0 + fr][ks * 32 + fg * 8];
      bf16x8 b1 = *(const bf16x8*)&Bbuf[16 + fr][ks * 32 + fg * 8];
      bf16x8 b2 = *(const bf16x8*)&Bbuf[32 + fr][ks * 32 + fg * 8];
      bf16x8 b3 = *(const bf16x8*)&Bbuf[48 + fr][ks * 32 + fg * 8];
      acc0 = __builtin_amdgcn_mfma_f32_16x16x32_bf16(af, b0, acc0, 0, 0, 0);
      acc1 = __builtin_amdgcn_mfma_f32_16x16x32_bf16(af, b1, acc1, 0, 0, 0);
      acc2 = __builtin_amdgcn_mfma_f32_16x16x32_bf16(af, b2, acc2, 0, 0, 0);
      acc3 = __builtin_amdgcn_mfma_f32_16x16x32_bf16(af, b3, acc3, 0, 0, 0);
    }
    __syncthreads();
  }

  const int orow = m0 + wv * 16 + fg * 4;  // + r  (C/D row mapping, m89)
  if (!kpath) {
    #pragma unroll
    for (int r = 0; r < 4; r++) {
      size_t rowoff = (size_t)(b * 256 + orow + r) * 256 + n0 + fr;
      Eq[rowoff +  0] = __builtin_amdgcn_exp2f(acc0[r] * SCALE_2LOG2E);
      Eq[rowoff + 16] = __builtin_amdgcn_exp2f(acc1[r] * SCALE_2LOG2E);
      Eq[rowoff + 32] = __builtin_amdgcn_exp2f(acc2[r] * SCALE_2LOG2E);
      Eq[rowoff + 48] = __builtin_amdgcn_exp2f(acc3[r] * SCALE_2LOG2E);
    }
  } else {
    #pragma unroll
    for (int r = 0; r < 4; r++) {
      size_t rowoff = (size_t)(b * 256 + orow + r) * 256 + n0 + fr;
      EkT[rowoff +  0] = (ushort)f2bf(__builtin_amdgcn_exp2f(acc0[r] * SCALE_2LOG2E));
      EkT[rowoff + 16] = (ushort)f2bf(__builtin_amdgcn_exp2f(acc1[r] * SCALE_2LOG2E));
      EkT[rowoff + 32] = (ushort)f2bf(__builtin_amdgcn_exp2f(acc2[r] * SCALE_2LOG2E));
      EkT[rowoff + 48] = (ushort)f2bf(__builtin_amdgcn_exp2f(acc3[r] * SCALE_2LOG2E));
    }
  }
}

// ---------------------------------------------------------------------------
// Kernel 2: scores + softmax.  QB=2, 512 thr, grid 1024 (32 waves/CU).
// EkT is bf16: uint2 per 4 k (8 B/lane, half the L1-port cycles and half the
// L2 traffic of r17's float4 loads); unpack = 1 shift/AND per value.
// eq/wv via wave-uniform s_loads (f32).
// ---------------------------------------------------------------------------
__global__ __launch_bounds__(512) void score_kernel(
    const float* __restrict__ Eq, const ushort* __restrict__ EkT,
    const float* __restrict__ wv, float* __restrict__ attn) {
  const int t    = threadIdx.x;
  const int wid  = __builtin_amdgcn_readfirstlane(t >> 6);   // wave-uniform
  const int lane = t & 63;
  const int b    = blockIdx.x & 7;         // XCD-locality decode
  const int q0   = (blockIdx.x >> 3) * QB;

  __shared__ float rbuf[4 * QB * 256];     // 8 KB: two-pass partial slots

  float4 s2v[QB];
  #pragma unroll
  for (int qq = 0; qq < QB; qq++) s2v[qq] = make_float4(0.f, 0.f, 0.f, 0.f);

  const int hbase = wid * 32;
  const ushort* ekb = EkT + (size_t)b * H_ * K_ + (size_t)hbase * K_ + 4 * lane;
  const float* eq0 = Eq + ((size_t)(b * Q_ + q0)) * H_ + hbase;
  const float* wv0 = wv + hbase;

  for (int st = 0; st < 8; st++) {         // 4 h per step
    float4 ekc[4];
    #pragma unroll
    for (int j = 0; j < 4; j++) {
      uint2 w = *(const uint2*)(ekb + (size_t)(st * 4 + j) * K_);
      ekc[j].x = __uint_as_float(w.x << 16);
      ekc[j].y = __uint_as_float(w.x & 0xFFFF0000u);
      ekc[j].z = __uint_as_float(w.y << 16);
      ekc[j].w = __uint_as_float(w.y & 0xFFFF0000u);
    }
    const int h = st * 4;
    float4 wvv  = *(const float4*)&wv0[h];             // uniform -> s_load
    float4 eqv0 = *(const float4*)&eq0[0 * H_ + h];    // uniform -> s_load
    float4 eqv1 = *(const float4*)&eq0[1 * H_ + h];
    #define SCORE_QC(qq, eqv, C)                                              \
    {                                                                         \
      float d0 = fmaf(eqv.x, ekc[0].C, 1.0f);                                 \
      float d1 = fmaf(eqv.y, ekc[1].C, 1.0f);                                 \
      float d2 = fmaf(eqv.z, ekc[2].C, 1.0f);                                 \
      float d3 = fmaf(eqv.w, ekc[3].C, 1.0f);                                 \
      float p01 = d0 * d1, p23 = d2 * d3;                                     \
      float n01 = fmaf(wvv.x, d1, wvv.y * d0);                                \
      float n23 = fmaf(wvv.z, d3, wvv.w * d2);                                \
      float num = fmaf(n01, p23, n23 * p01);                                  \
      s2v[qq].C = fmaf(num, __builtin_amdgcn_rcpf(p01 * p23), s2v[qq].C);     \
    }
    SCORE_QC(0, eqv0, x) SCORE_QC(0, eqv0, y) SCORE_QC(0, eqv0, z) SCORE_QC(0, eqv0, w)
    SCORE_QC(1, eqv1, x) SCORE_QC(1, eqv1, y) SCORE_QC(1, eqv1, z) SCORE_QC(1, eqv1, w)
    #undef SCORE_QC
  }

  // ---- two-pass combine into 4 slots (contiguous runs, conflict-free) ----
  if (wid >= 4) {
    #pragma unroll
    for (int qq = 0; qq < QB; qq++)
      *(float4*)&rbuf[(wid - 4) * (QB * 256) + qq * 256 + 4 * lane] = s2v[qq];
  }
  __syncthreads();
  if (wid < 4) {
    #pragma unroll
    for (int qq = 0; qq < QB; qq++) {
      float* p = &rbuf[wid * (QB * 256) + qq * 256 + 4 * lane];
      float4 o = *(const float4*)p;
      o.x += s2v[qq].x; o.y += s2v[qq].y; o.z += s2v[qq].z; o.w += s2v[qq].w;
      *(float4*)p = o;
    }
  }
  __syncthreads();

  // ---- softmax + normalized store: wave qg owns row qg; lane holds 4 k ----
  if (wid < QB) {
    const int qg = wid;
    float4 sc = make_float4(0.f, 0.f, 0.f, 0.f);
    #pragma unroll
    for (int s = 0; s < 4; s++) {
      float4 p = *(const float4*)&rbuf[s * (QB * 256) + qg * 256 + 4 * lane];
      sc.x += p.x; sc.y += p.y; sc.z += p.z; sc.w += p.w;
    }
    sc.x *= -2.0f; sc.y *= -2.0f; sc.z *= -2.0f; sc.w *= -2.0f;
    float m = fmaxf(fmaxf(sc.x, sc.y), fmaxf(sc.z, sc.w));
    #pragma unroll
    for (int mask = 32; mask >= 1; mask >>= 1) m = fmaxf(m, __shfl_xor(m, mask));
    float4 e;
    e.x = __builtin_amdgcn_exp2f((sc.x - m) * LOG2E_F);
    e.y = __builtin_amdgcn_exp2f((sc.y - m) * LOG2E_F);
    e.z = __builtin_amdgcn_exp2f((sc.z - m) * LOG2E_F);
    e.w = __builtin_amdgcn_exp2f((sc.w - m) * LOG2E_F);
    float sl = (e.x + e.y) + (e.z + e.w);
    #pragma unroll
    for (int mask = 32; mask >= 1; mask >>= 1) sl += __shfl_xor(sl, mask);
    float rs = __builtin_amdgcn_rcpf(sl);
    float4 o = make_float4(e.x * rs, e.y * rs, e.z * rs, e.w * rs);
    *(float4*)&attn[((size_t)(b * Q_ + q0 + qg)) * K_ + 4 * lane] = o;
  }
}

// ---------------------------------------------------------------------------
// Kernel 3: PV GEMM via bf16 MFMA: out[b] = attn[b] @ values[b].
// A = attn (direct stage), B = values^T (trans stage). attn pre-normalized.
// ---------------------------------------------------------------------------
__global__ __launch_bounds__(256) void pv_kernel(
    const float* __restrict__ attn, const float* __restrict__ values,
    float* __restrict__ out) {
  const int id  = blockIdx.x;
  const int b   = id & 7;
  const int m0  = ((id >> 3) & 3) * 64;    // q rows
  const int n0  = (id >> 5) * 64;          // dv cols (0..7)
  const int t   = threadIdx.x;

  __shared__ ushort Abuf[64][72];
  __shared__ ushort Bbuf[64][72];

  const int wv = t >> 6, l = t & 63, fr = l & 15, fg = l >> 4;

  f32x4 acc0 = {0.f, 0.f, 0.f, 0.f};
  f32x4 acc1 = acc0, acc2 = acc0, acc3 = acc0;

  for (int kk = 0; kk < K_; kk += 64) {
    stage_direct(attn + (size_t)(b * Q_ + m0) * K_ + kk, K_, Abuf, t);
    stage_trans (values + (size_t)(b * K_ + kk) * DV_ + n0, DV_, Bbuf, t);
    __syncthreads();
    #pragma unroll
    for (int ks = 0; ks < 2; ks++) {
      bf16x8 af = *(const bf16x8*)&Abuf[wv * 16 + fr][ks * 32 + fg * 8];
      bf16x8 b0 = *(const bf16x8*)&Bbuf[ 0 + fr][ks * 32 + fg * 8];
      bf16x8 b1 = *(const bf16x8*)&Bbuf[16 + fr][ks * 32 + fg * 8];
      bf16x8 b2 = *(const bf16x8*)&Bbuf[32 + fr][ks * 32 + fg * 8];
      bf16x8 b3 = *(const bf16x8*)&Bbuf[48 + fr][ks * 32 + fg * 8];
      acc0 = __builtin_amdgcn_mfma_f32_16x16x32_bf16(af, b0, acc0, 0, 0, 0);
      acc1 = __builtin_amdgcn_mfma_f32_16x16x32_bf16(af, b1, acc1, 0, 0, 0);
      acc2 = __builtin_amdgcn_mfma_f32_16x16x32_bf16(af, b2, acc2, 0, 0, 0);
      acc3 = __builtin_amdgcn_mfma_f32_16x16x32_bf16(af, b3, acc3, 0, 0, 0);
    }
    __syncthreads();
  }

  const int orow = m0 + wv * 16 + fg * 4;
  #pragma unroll
  for (int r = 0; r < 4; r++) {
    size_t rowoff = (size_t)(b * Q_ + orow + r) * DV_ + n0 + fr;
    out[rowoff +  0] = acc0[r];
    out[rowoff + 16] = acc1[r];
    out[rowoff + 32] = acc2[r];
    out[rowoff + 48] = acc3[r];
  }
}

extern "C" void kernel_launch(void* const* d_in, const int* in_sizes, int n_in,
                              void* d_out, int out_size, void* d_ws, size_t ws_size,
                              hipStream_t stream) {
  const float* queries = (const float*)d_in[0];  // [8,256,256]
  const float* keys    = (const float*)d_in[1];  // [8,256,256]
  const float* values  = (const float*)d_in[2];  // [8,256,512]
  const float* W_q     = (const float*)d_in[3];  // [256,256]
  const float* W_k     = (const float*)d_in[4];  // [256,256]
  const float* w_v     = (const float*)d_in[5];  // [256]
  float* out = (float*)d_out;

  float*  Eq   = (float*)d_ws;                   // [8][256][256] f32   = 2 MB
  ushort* EkT  = (ushort*)(Eq + (size_t)B_ * Q_ * H_);  // bf16          = 1 MB
  float*  attn = (float*)(EkT + (size_t)B_ * H_ * K_);  // f32           = 2 MB

  dim3 pgrid(256), pblk(256);
  proj_kernel<<<pgrid, pblk, 0, stream>>>(queries, keys, W_q, W_k, Eq, EkT);

  dim3 sgrid(Q_ / QB * B_), sblk(512);           // 1024 blocks
  score_kernel<<<sgrid, sblk, 0, stream>>>(Eq, EkT, w_v, attn);

  dim3 vgrid(256), vblk(256);
  pv_kernel<<<vgrid, vblk, 0, stream>>>(attn, values, out);
}

// Round 20
// 32.343 us; speedup vs baseline: 1.1472x; 1.1472x over previous
//
#include <hip/hip_runtime.h>
#include <hip/hip_bf16.h>

// Problem dims (fixed): B=8, Q=256, K=256, D=256, H=256, DV=512
#define B_  8
#define Q_  256
#define K_  256
#define D_  256
#define H_  256
#define DV_ 512
#define QB  2            // q-rows per score block

#define SCALE_2LOG2E 2.8853900817779268f   // 2*log2(e): exp(2x) = 2^(x*this)
#define LOG2E_F      1.4426950408889634f

typedef __attribute__((ext_vector_type(8))) short bf16x8;   // 8 bf16 = 4 VGPR
typedef __attribute__((ext_vector_type(4))) float f32x4;    // MFMA C/D

__device__ __forceinline__ uint f2bf(float f) {             // RNE f32->bf16
  uint u = __float_as_uint(f);
  return (u + 0x7FFFu + ((u >> 16) & 1u)) >> 16;
}
__device__ __forceinline__ uint pk(float lo, float hi) {
  return f2bf(lo) | (f2bf(hi) << 16);
}

// Stage a 64x64 f32 tile (row-major, leading dim ldg, base pre-offset) into
// LDS bf16 [64][72]. Direct layout.
__device__ __forceinline__ void stage_direct(const float* g, int ldg,
                                             ushort (*lds)[72], int t) {
  const int sr = t >> 2, sc = (t & 3) * 16;
  const float* sp = g + (size_t)sr * ldg + sc;
  float4 v0 = ((const float4*)sp)[0];
  float4 v1 = ((const float4*)sp)[1];
  float4 v2 = ((const float4*)sp)[2];
  float4 v3 = ((const float4*)sp)[3];
  uint4 w0, w1;
  w0.x = pk(v0.x, v0.y); w0.y = pk(v0.z, v0.w);
  w0.z = pk(v1.x, v1.y); w0.w = pk(v1.z, v1.w);
  w1.x = pk(v2.x, v2.y); w1.y = pk(v2.z, v2.w);
  w1.z = pk(v3.x, v3.y); w1.w = pk(v3.z, v3.w);
  *(uint4*)&lds[sr][sc]     = w0;
  *(uint4*)&lds[sr][sc + 8] = w1;
}
// Stage TRANSPOSED: global [kdim][rdim] (rdim contiguous, leading dim ldg,
// base pre-offset to (k0,r0)) -> LDS [r][k] bf16 via 4x4 register transpose.
__device__ __forceinline__ void stage_trans(const float* g, int ldg,
                                            ushort (*lds)[72], int t) {
  const int kq = (t & 15) * 4, rq = (t >> 4) * 4;
  float4 a0 = *(const float4*)(g + (size_t)(kq + 0) * ldg + rq);
  float4 a1 = *(const float4*)(g + (size_t)(kq + 1) * ldg + rq);
  float4 a2 = *(const float4*)(g + (size_t)(kq + 2) * ldg + rq);
  float4 a3 = *(const float4*)(g + (size_t)(kq + 3) * ldg + rq);
  uint2 w;
  w.x = pk(a0.x, a1.x); w.y = pk(a2.x, a3.x); *(uint2*)&lds[rq + 0][kq] = w;
  w.x = pk(a0.y, a1.y); w.y = pk(a2.y, a3.y); *(uint2*)&lds[rq + 1][kq] = w;
  w.x = pk(a0.z, a1.z); w.y = pk(a2.z, a3.z); *(uint2*)&lds[rq + 2][kq] = w;
  w.x = pk(a0.w, a1.w); w.y = pk(a2.w, a3.w); *(uint2*)&lds[rq + 3][kq] = w;
}

// ---------------------------------------------------------------------------
// Kernel 1: projections + exp, via bf16 MFMA (16x16x32).  [r18, session best]
//   qpath: Eq[q][h]  = exp2( (queries @ Wq) * 2log2e )   A=queries  B=Wq^T
//   kpath: EkT[h][k] = exp2( (Wk^T @ keys^T) * 2log2e )  A=Wk^T     B=keys
// 64x64 out-tile/block, 4 waves. C/D: row=(lane>>4)*4+r, col=lane&15
// [m89-verified]; A/B share the same k-window convention (k-permutation
// invariant for square CDNA shapes).
// ---------------------------------------------------------------------------
__global__ __launch_bounds__(256) void proj_kernel(
    const float* __restrict__ queries, const float* __restrict__ keys,
    const float* __restrict__ Wq, const float* __restrict__ Wk,
    float* __restrict__ Eq, float* __restrict__ EkT) {
  const int id = blockIdx.x;
  const int b  = id & 7;                   // XCD-locality decode
  const bool kpath = (id >> 3) & 1;
  const int m0 = ((id >> 4) & 3) * 64;     // qpath: q rows; kpath: h rows
  const int n0 = ((id >> 6) & 3) * 64;     // qpath: h cols; kpath: k cols
  const int t  = threadIdx.x;

  __shared__ ushort Abuf[64][72];          // 9 KB
  __shared__ ushort Bbuf[64][72];          // 9 KB

  const int wv = t >> 6, l = t & 63, fr = l & 15, fg = l >> 4;

  f32x4 acc0 = {0.f, 0.f, 0.f, 0.f};
  f32x4 acc1 = acc0, acc2 = acc0, acc3 = acc0;

  for (int kk = 0; kk < D_; kk += 64) {
    if (!kpath) {
      stage_direct(queries + (size_t)(b * Q_ + m0) * D_ + kk, D_, Abuf, t);
      stage_trans (Wq + (size_t)kk * H_ + n0, H_, Bbuf, t);
    } else {
      stage_trans (Wk + (size_t)kk * H_ + m0, H_, Abuf, t);
      stage_direct(keys + (size_t)(b * K_ + n0) * D_ + kk, D_, Bbuf, t);
    }
    __syncthreads();
    #pragma unroll
    for (int ks = 0; ks < 2; ks++) {
      bf16x8 af = *(const bf16x8*)&Abuf[wv * 16 + fr][ks * 32 + fg * 8];
      bf16x8 b0 = *(const bf16x8*)&Bbuf[ 0 + fr][ks * 32 + fg * 8];
      bf16x8 b1 = *(const bf16x8*)&Bbuf[16 + fr][ks * 32 + fg * 8];
      bf16x8 b2 = *(const bf16x8*)&Bbuf[32 + fr][ks * 32 + fg * 8];
      bf16x8 b3 = *(const bf16x8*)&Bbuf[48 + fr][ks * 32 + fg * 8];
      acc0 = __builtin_amdgcn_mfma_f32_16x16x32_bf16(af, b0, acc0, 0, 0, 0);
      acc1 = __builtin_amdgcn_mfma_f32_16x16x32_bf16(af, b1, acc1, 0, 0, 0);
      acc2 = __builtin_amdgcn_mfma_f32_16x16x32_bf16(af, b2, acc2, 0, 0, 0);
      acc3 = __builtin_amdgcn_mfma_f32_16x16x32_bf16(af, b3, acc3, 0, 0, 0);
    }
    __syncthreads();
  }

  float* dst = kpath ? EkT : Eq;
  const int orow = m0 + wv * 16 + fg * 4;  // + r  (C/D row mapping, m89)
  #pragma unroll
  for (int r = 0; r < 4; r++) {
    size_t rowoff = (size_t)(b * 256 + orow + r) * 256 + n0 + fr;
    dst[rowoff +  0] = __builtin_amdgcn_exp2f(acc0[r] * SCALE_2LOG2E);
    dst[rowoff + 16] = __builtin_amdgcn_exp2f(acc1[r] * SCALE_2LOG2E);
    dst[rowoff + 32] = __builtin_amdgcn_exp2f(acc2[r] * SCALE_2LOG2E);
    dst[rowoff + 48] = __builtin_amdgcn_exp2f(acc3[r] * SCALE_2LOG2E);
  }
}

// ---------------------------------------------------------------------------
// Kernel 2: scores + softmax (r17/r18 lean form).  QB=2, 512 thr, grid 1024.
// EkT f32 float4 loads (r19 proved bf16+unpack is slower); eq/wv via
// wave-uniform s_loads; 4-way h-combined sigmoids (1 rcp / 4 h).
// ---------------------------------------------------------------------------
__global__ __launch_bounds__(512) void score_kernel(
    const float* __restrict__ Eq, const float* __restrict__ EkT,
    const float* __restrict__ wv, float* __restrict__ attn) {
  const int t    = threadIdx.x;
  const int wid  = __builtin_amdgcn_readfirstlane(t >> 6);   // wave-uniform
  const int lane = t & 63;
  const int b    = blockIdx.x & 7;         // XCD-locality decode
  const int q0   = (blockIdx.x >> 3) * QB;

  __shared__ float rbuf[4 * QB * 256];     // 8 KB: two-pass partial slots

  float4 s2v[QB];
  #pragma unroll
  for (int qq = 0; qq < QB; qq++) s2v[qq] = make_float4(0.f, 0.f, 0.f, 0.f);

  const int hbase = wid * 32;
  const float* ekb = EkT + (size_t)b * H_ * K_ + (size_t)hbase * K_ + 4 * lane;
  const float* eq0 = Eq + ((size_t)(b * Q_ + q0)) * H_ + hbase;
  const float* wv0 = wv + hbase;

  for (int st = 0; st < 8; st++) {         // 4 h per step
    float4 ekc[4];
    #pragma unroll
    for (int j = 0; j < 4; j++)
      ekc[j] = *(const float4*)(ekb + (size_t)(st * 4 + j) * K_);
    const int h = st * 4;
    float4 wvv  = *(const float4*)&wv0[h];             // uniform -> s_load
    float4 eqv0 = *(const float4*)&eq0[0 * H_ + h];    // uniform -> s_load
    float4 eqv1 = *(const float4*)&eq0[1 * H_ + h];
    #define SCORE_QC(qq, eqv, C)                                              \
    {                                                                         \
      float d0 = fmaf(eqv.x, ekc[0].C, 1.0f);                                 \
      float d1 = fmaf(eqv.y, ekc[1].C, 1.0f);                                 \
      float d2 = fmaf(eqv.z, ekc[2].C, 1.0f);                                 \
      float d3 = fmaf(eqv.w, ekc[3].C, 1.0f);                                 \
      float p01 = d0 * d1, p23 = d2 * d3;                                     \
      float n01 = fmaf(wvv.x, d1, wvv.y * d0);                                \
      float n23 = fmaf(wvv.z, d3, wvv.w * d2);                                \
      float num = fmaf(n01, p23, n23 * p01);                                  \
      s2v[qq].C = fmaf(num, __builtin_amdgcn_rcpf(p01 * p23), s2v[qq].C);     \
    }
    SCORE_QC(0, eqv0, x) SCORE_QC(0, eqv0, y) SCORE_QC(0, eqv0, z) SCORE_QC(0, eqv0, w)
    SCORE_QC(1, eqv1, x) SCORE_QC(1, eqv1, y) SCORE_QC(1, eqv1, z) SCORE_QC(1, eqv1, w)
    #undef SCORE_QC
  }

  // ---- two-pass combine into 4 slots (contiguous runs, conflict-free) ----
  if (wid >= 4) {
    #pragma unroll
    for (int qq = 0; qq < QB; qq++)
      *(float4*)&rbuf[(wid - 4) * (QB * 256) + qq * 256 + 4 * lane] = s2v[qq];
  }
  __syncthreads();
  if (wid < 4) {
    #pragma unroll
    for (int qq = 0; qq < QB; qq++) {
      float* p = &rbuf[wid * (QB * 256) + qq * 256 + 4 * lane];
      float4 o = *(const float4*)p;
      o.x += s2v[qq].x; o.y += s2v[qq].y; o.z += s2v[qq].z; o.w += s2v[qq].w;
      *(float4*)p = o;
    }
  }
  __syncthreads();

  // ---- softmax + normalized store: wave qg owns row qg; lane holds 4 k ----
  if (wid < QB) {
    const int qg = wid;
    float4 sc = make_float4(0.f, 0.f, 0.f, 0.f);
    #pragma unroll
    for (int s = 0; s < 4; s++) {
      float4 p = *(const float4*)&rbuf[s * (QB * 256) + qg * 256 + 4 * lane];
      sc.x += p.x; sc.y += p.y; sc.z += p.z; sc.w += p.w;
    }
    sc.x *= -2.0f; sc.y *= -2.0f; sc.z *= -2.0f; sc.w *= -2.0f;
    float m = fmaxf(fmaxf(sc.x, sc.y), fmaxf(sc.z, sc.w));
    #pragma unroll
    for (int mask = 32; mask >= 1; mask >>= 1) m = fmaxf(m, __shfl_xor(m, mask));
    float4 e;
    e.x = __builtin_amdgcn_exp2f((sc.x - m) * LOG2E_F);
    e.y = __builtin_amdgcn_exp2f((sc.y - m) * LOG2E_F);
    e.z = __builtin_amdgcn_exp2f((sc.z - m) * LOG2E_F);
    e.w = __builtin_amdgcn_exp2f((sc.w - m) * LOG2E_F);
    float sl = (e.x + e.y) + (e.z + e.w);
    #pragma unroll
    for (int mask = 32; mask >= 1; mask >>= 1) sl += __shfl_xor(sl, mask);
    float rs = __builtin_amdgcn_rcpf(sl);
    float4 o = make_float4(e.x * rs, e.y * rs, e.z * rs, e.w * rs);
    *(float4*)&attn[((size_t)(b * Q_ + q0 + qg)) * K_ + 4 * lane] = o;
  }
}

// ---------------------------------------------------------------------------
// Kernel 3: PV GEMM via bf16 MFMA: out[b] = attn[b] @ values[b].
// A = attn (direct stage), B = values^T (trans stage). attn pre-normalized.
// ---------------------------------------------------------------------------
__global__ __launch_bounds__(256) void pv_kernel(
    const float* __restrict__ attn, const float* __restrict__ values,
    float* __restrict__ out) {
  const int id  = blockIdx.x;
  const int b   = id & 7;
  const int m0  = ((id >> 3) & 3) * 64;    // q rows
  const int n0  = (id >> 5) * 64;          // dv cols (0..7)
  const int t   = threadIdx.x;

  __shared__ ushort Abuf[64][72];
  __shared__ ushort Bbuf[64][72];

  const int wv = t >> 6, l = t & 63, fr = l & 15, fg = l >> 4;

  f32x4 acc0 = {0.f, 0.f, 0.f, 0.f};
  f32x4 acc1 = acc0, acc2 = acc0, acc3 = acc0;

  for (int kk = 0; kk < K_; kk += 64) {
    stage_direct(attn + (size_t)(b * Q_ + m0) * K_ + kk, K_, Abuf, t);
    stage_trans (values + (size_t)(b * K_ + kk) * DV_ + n0, DV_, Bbuf, t);
    __syncthreads();
    #pragma unroll
    for (int ks = 0; ks < 2; ks++) {
      bf16x8 af = *(const bf16x8*)&Abuf[wv * 16 + fr][ks * 32 + fg * 8];
      bf16x8 b0 = *(const bf16x8*)&Bbuf[ 0 + fr][ks * 32 + fg * 8];
      bf16x8 b1 = *(const bf16x8*)&Bbuf[16 + fr][ks * 32 + fg * 8];
      bf16x8 b2 = *(const bf16x8*)&Bbuf[32 + fr][ks * 32 + fg * 8];
      bf16x8 b3 = *(const bf16x8*)&Bbuf[48 + fr][ks * 32 + fg * 8];
      acc0 = __builtin_amdgcn_mfma_f32_16x16x32_bf16(af, b0, acc0, 0, 0, 0);
      acc1 = __builtin_amdgcn_mfma_f32_16x16x32_bf16(af, b1, acc1, 0, 0, 0);
      acc2 = __builtin_amdgcn_mfma_f32_16x16x32_bf16(af, b2, acc2, 0, 0, 0);
      acc3 = __builtin_amdgcn_mfma_f32_16x16x32_bf16(af, b3, acc3, 0, 0, 0);
    }
    __syncthreads();
  }

  const int orow = m0 + wv * 16 + fg * 4;
  #pragma unroll
  for (int r = 0; r < 4; r++) {
    size_t rowoff = (size_t)(b * Q_ + orow + r) * DV_ + n0 + fr;
    out[rowoff +  0] = acc0[r];
    out[rowoff + 16] = acc1[r];
    out[rowoff + 32] = acc2[r];
    out[rowoff + 48] = acc3[r];
  }
}

extern "C" void kernel_launch(void* const* d_in, const int* in_sizes, int n_in,
                              void* d_out, int out_size, void* d_ws, size_t ws_size,
                              hipStream_t stream) {
  const float* queries = (const float*)d_in[0];  // [8,256,256]
  const float* keys    = (const float*)d_in[1];  // [8,256,256]
  const float* values  = (const float*)d_in[2];  // [8,256,512]
  const float* W_q     = (const float*)d_in[3];  // [256,256]
  const float* W_k     = (const float*)d_in[4];  // [256,256]
  const float* w_v     = (const float*)d_in[5];  // [256]
  float* out = (float*)d_out;

  float* Eq   = (float*)d_ws;                    // [8][256][256] = 2 MB
  float* EkT  = Eq  + (size_t)B_ * Q_ * H_;      // [8][256][256] = 2 MB
  float* attn = EkT + (size_t)B_ * H_ * K_;      // [8][256][256] = 2 MB

  dim3 pgrid(256), pblk(256);
  proj_kernel<<<pgrid, pblk, 0, stream>>>(queries, keys, W_q, W_k, Eq, EkT);

  dim3 sgrid(Q_ / QB * B_), sblk(512);           // 1024 blocks
  score_kernel<<<sgrid, sblk, 0, stream>>>(Eq, EkT, w_v, attn);

  dim3 vgrid(256), vblk(256);
  pv_kernel<<<vgrid, vblk, 0, stream>>>(attn, values, out);
}